// Round 5
// baseline (222.089 us; speedup 1.0000x reference)
//
#include <hip/hip_runtime.h>
#include <cstdint>
#include <cstddef>

#define B_  4
#define S_  2048
#define H_  12
#define DH  64
#define DM  768

typedef unsigned short u16;
typedef __bf16 bf16x8 __attribute__((ext_vector_type(8)));
typedef float f32x4 __attribute__((ext_vector_type(4)));

__device__ __forceinline__ u16 f2bf(float f) {
  unsigned u = __float_as_uint(f);
  u += 0x7FFFu + ((u >> 16) & 1u);   // RNE
  return (u16)(u >> 16);
}

__device__ __forceinline__ void gl16(const u16* g, u16* l) {
  __builtin_amdgcn_global_load_lds((const __attribute__((address_space(1))) void*)g,
                                   (__attribute__((address_space(3))) void*)l,
                                   16, 0, 0);
}

// ---------------- prep: x->bf16 + mask flags + W transpose (one launch) ----------------
// blocks [0, 6144): x cvt (+mflags for first 64); blocks [6144, 7872): wtrans
__global__ __launch_bounds__(256) void k_prep(const float* __restrict__ x, u16* __restrict__ xb,
                                              const int* __restrict__ mask, int* __restrict__ mflags,
                                              const float* __restrict__ Wq, const float* __restrict__ Wk,
                                              const float* __restrict__ Wv, u16* __restrict__ Wt) {
  const int bid = blockIdx.x;
  if (bid < 6144) {
    int i = bid * 256 + threadIdx.x;
    const float4 v = ((const float4*)x)[i];
    ushort4 o;
    o.x = f2bf(v.x); o.y = f2bf(v.y); o.z = f2bf(v.z); o.w = f2bf(v.w);
    ((ushort4*)xb)[i] = o;
    if (bid < 64) {
      __shared__ int f;
      if (threadIdx.x == 0) f = 0;
      __syncthreads();
      if (threadIdx.x < 128 && mask[bid * 128 + threadIdx.x] != 1) f = 1;
      __syncthreads();
      if (threadIdx.x == 0) mflags[bid] = f;
    }
  } else {
    const int b2 = bid - 6144;
    const int z = b2 / 576, rem = b2 % 576;
    const int by = rem / 24, bx = rem % 24;
    const float* W = z == 0 ? Wq : (z == 1 ? Wk : Wv);
    u16* o = Wt + (size_t)z * DM * DM;
    __shared__ float t[32][33];
    const int xx = threadIdx.x & 31, yy = threadIdx.x >> 5;  // (32,8)
    const int n0 = bx * 32, k0 = by * 32;
#pragma unroll
    for (int i = 0; i < 4; i++)
      t[yy + i*8][xx] = W[(size_t)(k0 + yy + i*8)*DM + n0 + xx];
    __syncthreads();
#pragma unroll
    for (int i = 0; i < 4; i++)
      o[(size_t)(n0 + yy + i*8)*DM + k0 + xx] = f2bf(t[xx][yy + i*8]);
  }
}

// ---------------- fused QKV projection GEMM ----------------
// Block tile 128(m) x 256(n), wave tile 64x128 (acc 4x8), BK=32 double-buffered.
// n-dim spans all 3 mats (2304): mat = blockIdx.x / 3 (no straddle at 256 granularity).
// mat 0: Q (pre-scaled by 0.125*log2e); mat 1: K; mat 2: V written transposed to Vt[bh][d][t].
__global__ __launch_bounds__(256, 2) void k_qkv(const u16* __restrict__ Xb, const u16* __restrict__ Wt,
                                                const float* __restrict__ bq, const float* __restrict__ bk,
                                                const float* __restrict__ bv, u16* __restrict__ QKV,
                                                u16* __restrict__ Vt) {
  const int n0 = blockIdx.x * 256, m0 = blockIdx.y * 128;
  const int mat = blockIdx.x / 3;
  const int n0r = n0 - mat * 768;
  const float* bias = mat == 0 ? bq : (mat == 1 ? bk : bv);
  __shared__ __align__(16) u16 Al[2*128*32];   // 16 KB
  __shared__ __align__(16) u16 Bl[2*256*32];   // 32 KB
  const int tid = threadIdx.x, w = tid >> 6, l = tid & 63, l15 = l & 15, quad = l >> 4;
  const int wm = w & 1, wn = w >> 1;
  f32x4 acc[4][8];
#pragma unroll
  for (int i = 0; i < 4; i++)
#pragma unroll
    for (int j = 0; j < 8; j++) acc[i][j] = f32x4{0.f, 0.f, 0.f, 0.f};

  // staging lane offsets: A 512 chunks (2/thread), B 1024 chunks (4/thread)
  int aoff[2], boff[4];
#pragma unroll
  for (int i = 0; i < 2; i++) {
    int c = tid + i*256;
    int r = c >> 2, s = c & 3, sl = s ^ ((r ^ (r >> 2)) & 3);
    aoff[i] = r*DM + sl*8;
  }
#pragma unroll
  for (int i = 0; i < 4; i++) {
    int c = tid + i*256;
    int r = c >> 2, s = c & 3, sl = s ^ ((r ^ (r >> 2)) & 3);
    boff[i] = r*DM + sl*8;
  }
  const u16* ap = Xb + (size_t)m0 * DM;
  const u16* bp = Wt + (size_t)n0 * DM;

#define STAGE(kt) {                                             \
    int ab = ((kt) & 1) * 4096, bb = ((kt) & 1) * 8192;         \
    _Pragma("unroll")                                           \
    for (int i = 0; i < 2; i++)                                 \
      gl16(ap + (kt)*32 + aoff[i], Al + ab + (tid + i*256)*8);  \
    _Pragma("unroll")                                           \
    for (int i = 0; i < 4; i++)                                 \
      gl16(bp + (kt)*32 + boff[i], Bl + bb + (tid + i*256)*8);  \
  }

  STAGE(0)
  for (int kt = 0; kt < DM/32; ++kt) {
    __syncthreads();                 // DMA(kt) done (issued one compute-phase ago)
    if (kt + 1 < DM/32) STAGE(kt+1)
    const int ab = (kt & 1) * 4096, bb = (kt & 1) * 8192;
    bf16x8 af[4], bfr[8];
#pragma unroll
    for (int mt = 0; mt < 4; mt++) {
      int row = wm*64 + mt*16 + l15;
      int ph = quad ^ ((row ^ (row >> 2)) & 3);
      af[mt] = *(const bf16x8*)(Al + ab + row*32 + ph*8);
    }
#pragma unroll
    for (int nt = 0; nt < 8; nt++) {
      int row = wn*128 + nt*16 + l15;
      int ph = quad ^ ((row ^ (row >> 2)) & 3);
      bfr[nt] = *(const bf16x8*)(Bl + bb + row*32 + ph*8);
    }
#pragma unroll
    for (int mt = 0; mt < 4; mt++)
#pragma unroll
      for (int nt = 0; nt < 8; nt++)
        acc[mt][nt] = __builtin_amdgcn_mfma_f32_16x16x32_bf16(af[mt], bfr[nt], acc[mt][nt], 0, 0, 0);
  }
#undef STAGE

  float b8[8];
#pragma unroll
  for (int nt = 0; nt < 8; nt++) b8[nt] = bias[n0r + wn*128 + nt*16 + l15];

  if (mat == 2) {
    // V transposed: Vt[(b*H+h)*DH + d][t], 4 t per ushort4 store
#pragma unroll
    for (int mt = 0; mt < 4; mt++) {
      int gm = m0 + wm*64 + mt*16 + quad*4;
      int b = gm >> 11, t = gm & 2047;
#pragma unroll
      for (int nt = 0; nt < 8; nt++) {
        int ng = n0r + wn*128 + nt*16;
        int h = ng >> 6, d = (ng & 63) + l15;
        ushort4 o;
        o.x = f2bf(acc[mt][nt][0] + b8[nt]);
        o.y = f2bf(acc[mt][nt][1] + b8[nt]);
        o.z = f2bf(acc[mt][nt][2] + b8[nt]);
        o.w = f2bf(acc[mt][nt][3] + b8[nt]);
        *(ushort4*)(Vt + ((size_t)(b*H_ + h)*DH + d)*S_ + t) = o;
      }
    }
  } else {
    const float osc = (mat == 0) ? (0.125f * 1.44269504f) : 1.0f;
    u16* outm = QKV + (size_t)mat * (size_t)(B_*S_) * DM;
#pragma unroll
    for (int mt = 0; mt < 4; mt++)
#pragma unroll
      for (int r = 0; r < 4; r++) {
        int gm = m0 + wm*64 + mt*16 + quad*4 + r;
        u16* orow = outm + (size_t)gm*DM + n0r + wn*128;
#pragma unroll
        for (int nt = 0; nt < 8; nt++)
          orow[nt*16 + l15] = f2bf((acc[mt][nt][r] + b8[nt]) * osc);
      }
  }
}

// ---------------- flash attention: 4 waves x 64 q (q-tile 256), t-tile 128 ----------------
__global__ __launch_bounds__(256, 2) void k_attn(const u16* __restrict__ Qb, const u16* __restrict__ Kb,
                                                 const u16* __restrict__ Vt, const int* __restrict__ mask,
                                                 const int* __restrict__ mflags, float* __restrict__ out) {
  const int bh = blockIdx.x, b = bh / H_, h = bh % H_;
  const int q0 = blockIdx.y * 256;
  __shared__ __align__(16) u16 Kl[128*64];        // 16 KB, src-XOR swizzled
  __shared__ __align__(16) u16 Vl[64*128];        // 16 KB, src-XOR swizzled
  __shared__ __align__(16) u16 QP[4*64*72];       // Q stage (32 KB) then per-wave P [64][72] (36.9 KB)
  __shared__ __align__(16) float maskl[128];
  const int tid = threadIdx.x, w = tid >> 6, l = tid & 63, l15 = l & 15, quad = l >> 4;

  // stage Q tile (256 rows x 64: 2048 chunks, 8/thread)
#pragma unroll
  for (int i = 0; i < 8; i++) {
    int c = tid + i*256;
    int r = c >> 3, s = c & 7, sl = s ^ (r & 7);
    gl16(Qb + (size_t)(b*S_ + q0 + r)*DM + h*DH + sl*8, QP + c*8);
  }
  __syncthreads();
  bf16x8 qf[4][2];  // B-operand frags: B[k=d][n=q], 64 q per wave
#pragma unroll
  for (int nt = 0; nt < 4; nt++)
#pragma unroll
    for (int ks = 0; ks < 2; ks++) {
      int r = w*64 + nt*16 + l15;
      int ph = (ks*4 + quad) ^ (r & 7);
      qf[nt][ks] = *(const bf16x8*)(QP + r*64 + ph*8);
    }
  __syncthreads();  // before QP reuse as P

  f32x4 O[4][4], Ol[4];
#pragma unroll
  for (int i = 0; i < 4; i++) {
    Ol[i] = f32x4{0.f, 0.f, 0.f, 0.f};
#pragma unroll
    for (int j = 0; j < 4; j++) O[i][j] = f32x4{0.f, 0.f, 0.f, 0.f};
  }
  const f32x4 ZV = {0.f, 0.f, 0.f, 0.f};
  bf16x8 vone;
#pragma unroll
  for (int j = 0; j < 8; j++) vone[j] = (l15 == 0) ? (__bf16)1.0f : (__bf16)0.0f;
  u16* Pw = QP + w*64*72;

  // staging lane offsets (K: 1024 chunks; V: 1024 chunks; 4/thread each)
  int koff[4], voff[4];
#pragma unroll
  for (int i = 0; i < 4; i++) {
    int c = tid + i*256;
    { int r = c >> 3, s = c & 7, sl = s ^ (r & 7);   koff[i] = r*DM + sl*8; }
    { int r = c >> 4, s = c & 15, sl = s ^ (r & 15); voff[i] = r*S_ + sl*8; }
  }
  const u16* kp = Kb + (size_t)(b*S_)*DM + h*DH;
  const u16* vp = Vt + (size_t)bh*DH*S_;

  for (int tt = 0; tt < S_/128; ++tt) {
    __syncthreads();
#pragma unroll
    for (int i = 0; i < 4; i++) {
      int c = tid + i*256;
      gl16(kp + koff[i], Kl + c*8);
      gl16(vp + voff[i], Vl + c*8);
    }
    kp += 128*DM; vp += 128;
    const int mflag = mflags[b*16 + tt];
    if (mflag && tid < 128)
      maskl[tid] = (1.0f - (float)mask[b*S_ + tt*128 + tid]) * (-10000.0f * 1.44269504f);
    __syncthreads();

    // two halves of 64 t each: St half -> exp2/pack -> PV half
#pragma unroll
    for (int h2 = 0; h2 < 2; ++h2) {
      f32x4 sc[4][4];
#pragma unroll
      for (int mt = 0; mt < 4; mt++) {
        int row = h2*64 + mt*16 + l15;
        bf16x8 k0f = *(const bf16x8*)(Kl + row*64 + ((quad    ) ^ (row & 7))*8);
        bf16x8 k1f = *(const bf16x8*)(Kl + row*64 + ((4 + quad) ^ (row & 7))*8);
#pragma unroll
        for (int nt = 0; nt < 4; nt++) {
          sc[mt][nt] = __builtin_amdgcn_mfma_f32_16x16x32_bf16(k0f, qf[nt][0], ZV, 0, 0, 0);
          sc[mt][nt] = __builtin_amdgcn_mfma_f32_16x16x32_bf16(k1f, qf[nt][1], sc[mt][nt], 0, 0, 0);
        }
      }
      if (mflag) {
#pragma unroll
        for (int mt = 0; mt < 4; mt++) {
          f32x4 mv = *(const f32x4*)&maskl[h2*64 + mt*16 + quad*4];
#pragma unroll
          for (int nt = 0; nt < 4; nt++)
#pragma unroll
            for (int r = 0; r < 4; r++) sc[mt][nt][r] += mv[r];
        }
      }
      // raw exp2 + truncate-to-bf16 pack (v_perm) + store P
#pragma unroll
      for (int nt = 0; nt < 4; nt++)
#pragma unroll
        for (int mt = 0; mt < 4; mt++) {
          unsigned u[4];
#pragma unroll
          for (int r = 0; r < 4; r++) u[r] = __float_as_uint(__builtin_amdgcn_exp2f(sc[mt][nt][r]));
          uint2 pk;
          pk.x = __builtin_amdgcn_perm(u[1], u[0], 0x07060302u);
          pk.y = __builtin_amdgcn_perm(u[3], u[2], 0x07060302u);
          *(uint2*)(Pw + (nt*16 + l15)*72 + mt*16 + quad*4) = pk;
        }
      asm volatile("s_waitcnt lgkmcnt(0)" ::: "memory");
      // O += P·V ; Ol += P·ones (row sums, exact normalization)
#pragma unroll
      for (int kk = 0; kk < 2; kk++) {
        int ksg = h2*2 + kk;
        bf16x8 pa[4], vb[4];
#pragma unroll
        for (int mo = 0; mo < 4; mo++)
          pa[mo] = *(const bf16x8*)(Pw + (mo*16 + l15)*72 + kk*32 + quad*8);
#pragma unroll
        for (int nd = 0; nd < 4; nd++) {
          int d = nd*16 + l15;
          int ph = (ksg*4 + quad) ^ (d & 15);
          vb[nd] = *(const bf16x8*)(Vl + d*128 + ph*8);
        }
#pragma unroll
        for (int mo = 0; mo < 4; mo++) {
#pragma unroll
          for (int nd = 0; nd < 4; nd++)
            O[mo][nd] = __builtin_amdgcn_mfma_f32_16x16x32_bf16(pa[mo], vb[nd], O[mo][nd], 0, 0, 0);
          Ol[mo] = __builtin_amdgcn_mfma_f32_16x16x32_bf16(pa[mo], vone, Ol[mo], 0, 0, 0);
        }
      }
    }
  }

  // epilogue: l lives in Ol at lanes l15==0; broadcast within 16-lane group
#pragma unroll
  for (int mo = 0; mo < 4; mo++)
#pragma unroll
    for (int r = 0; r < 4; r++) {
      float lsum = __shfl(Ol[mo][r], l & 48);
      float inv = 1.0f / lsum;
      int q = q0 + w*64 + mo*16 + quad*4 + r;
      float* orow = out + (size_t)(b*S_ + q)*DM + h*DH;
#pragma unroll
      for (int nd = 0; nd < 4; nd++)
        orow[nd*16 + l15] = O[mo][nd][r] * inv;
    }
}

extern "C" void kernel_launch(void* const* d_in, const int* in_sizes, int n_in,
                              void* d_out, int out_size, void* d_ws, size_t ws_size,
                              hipStream_t stream) {
  const float* x  = (const float*)d_in[0];
  const float* Wq = (const float*)d_in[1];
  const float* bq = (const float*)d_in[2];
  const float* Wk = (const float*)d_in[3];
  const float* bk = (const float*)d_in[4];
  const float* Wv = (const float*)d_in[5];
  const float* bv = (const float*)d_in[6];
  const int* mask = (const int*)d_in[7];
  float* out = (float*)d_out;

  u16* Xb  = (u16*)d_ws;                            // 12.6 MB
  u16* Wt  = Xb  + (size_t)B_*S_*DM;                // 3.5 MB (flat [2304][768])
  u16* QKV = Wt  + (size_t)3*DM*DM;                 // planes Q,K used
  u16* Vt  = QKV + (size_t)3*B_*S_*DM;              // 12.6 MB
  int* mflags = (int*)(Vt + (size_t)B_*S_*DM);      // 256 B

  k_prep<<<dim3(6144 + 1728), dim3(256), 0, stream>>>(x, Xb, mask, mflags, Wq, Wk, Wv, Wt);
  k_qkv <<<dim3(9, 64), dim3(256), 0, stream>>>(Xb, Wt, bq, bk, bv, QKV, Vt);
  k_attn<<<dim3(B_*H_, S_/256), dim3(256), 0, stream>>>(QKV, QKV + (size_t)B_*S_*DM, Vt, mask, mflags, out);
}